// Round 12
// baseline (208.078 us; speedup 1.0000x reference)
//
#include <hip/hip_runtime.h>
#include <math.h>

// ---------------------------------------------------------------------------
// RNN_6451040879094  (B=4096, I=H=1024, O=4096, fp32 in/out)
// R12: - gemm8p LOCKED at R10 form (best measured 69.0-69.6us across 5
//        schedule variants; R11 form was ~71-73).
//      - front-end overlap: f2bA converts only GEMM1's inputs (x, hid0, W0);
//        cvtB (hid1, W1s, W_out; 84MB) fused into GEMM1's dispatch as 512
//        grid-strided blocks (~2 cvt blocks/CU — R6's failure was 7168
//        unthrottled blocks starving the GEMM).
//      - logsoftmax float4-vectorized (R11).
// d_out: out(4096*4096) ++ h0(4096*1024) ++ h1(4096*1024), fp32.
// ---------------------------------------------------------------------------

typedef __attribute__((ext_vector_type(8))) short bf16x8;
typedef __attribute__((ext_vector_type(4))) float f32x4;

__device__ __forceinline__ unsigned short f2b_rne(float f) {
    unsigned int x = __float_as_uint(f);
    x += 0x7FFF + ((x >> 16) & 1);
    return (unsigned short)(x >> 16);
}

__device__ __forceinline__ void gload_lds16(const void* g, void* l) {
    __builtin_amdgcn_global_load_lds(
        (const __attribute__((address_space(1))) void*)g,
        (__attribute__((address_space(3))) void*)l,
        16, 0, 0);
}

// ---------------- fp32 -> bf16 conversion ----------------------------------
struct CvtSeg { const float* src; unsigned short* dst; unsigned n8; };
struct CvtArgs { CvtSeg seg[4]; };

__device__ __forceinline__ void cvt_do(const CvtArgs& a, unsigned i)
{
#pragma unroll
    for (int s = 0; s < 4; ++s) {
        if (i < a.seg[s].n8) {
            const float4* src = (const float4*)a.seg[s].src;
            float4 u = src[2 * (size_t)i];
            float4 v = src[2 * (size_t)i + 1];
            unsigned short t[8] = {
                f2b_rne(u.x), f2b_rne(u.y), f2b_rne(u.z), f2b_rne(u.w),
                f2b_rne(v.x), f2b_rne(v.y), f2b_rne(v.z), f2b_rne(v.w)};
            *(uint4*)(a.seg[s].dst + 8 * (size_t)i) = *(const uint4*)t;
            return;
        }
        i -= a.seg[s].n8;
    }
}

__global__ __launch_bounds__(256) void f2b_multi(CvtArgs a)
{
    cvt_do(a, blockIdx.x * 256u + threadIdx.x);
}

// ================= 2-phase 128xBN GEMM (GEMM1 / GEMM2 roles) ================
struct GemmP {
    const unsigned short *Aa, *Ab; int lda;
    const unsigned short *Wa, *Wb; int ldw;
    const float *ba, *bb;
    float* C; int ldc;
    unsigned short* Cb; int ldcb;
    int nx, nb, do_tanh;
};

template<int BM, int BN>
__device__ __forceinline__ void gemm2p_body(
    const GemmP& p, int bid0, unsigned short* As, unsigned short* Ws, int tid)
{
    constexpr int FM = BM / 32;
    constexpr int FN = BN / 32;
    int bid = (bid0 & 7) * (p.nb >> 3) + (bid0 >> 3);
    const int row0 = (bid / p.nx) * BM;
    const int col0 = (bid % p.nx) * BN;

    const int wid = tid >> 6, lane = tid & 63;
    const int wr = wid >> 1, wc = wid & 1;
    const int fr = lane & 15, fk = lane >> 4;

    f32x4 acc[FM][FN] = {};

    for (int h = 0; h < 2; ++h) {
        const unsigned short* A = h ? p.Ab : p.Aa;
        const unsigned short* W = h ? p.Wb : p.Wa;
        for (int k0 = 0; k0 < 1024; k0 += 32) {
#pragma unroll
            for (int i = 0; i < BM / 64; ++i) {
                int c = i * 256 + wid * 64 + lane;
                int r = c >> 2, ol = c & 3;
                int os = ol ^ ((r >> 1) & 3);
                gload_lds16(A + (size_t)(row0 + r) * p.lda + k0 + os * 8,
                            As + (i * 256 + wid * 64) * 8);
            }
#pragma unroll
            for (int i = 0; i < BN / 64; ++i) {
                int c = i * 256 + wid * 64 + lane;
                int r = c >> 2, ol = c & 3;
                int os = ol ^ ((r >> 1) & 3);
                gload_lds16(W + (size_t)(col0 + r) * p.ldw + k0 + os * 8,
                            Ws + (i * 256 + wid * 64) * 8);
            }
            __syncthreads();   // full vmcnt(0)+lgkmcnt(0) drain + barrier

            bf16x8 af[FM], wf[FN];
#pragma unroll
            for (int m = 0; m < FM; ++m) {
                int r = wr * (BM / 2) + m * 16 + fr;
                af[m] = *(const bf16x8*)&As[r * 32 + ((fk ^ ((r >> 1) & 3)) * 8)];
            }
#pragma unroll
            for (int n = 0; n < FN; ++n) {
                int r = wc * (BN / 2) + n * 16 + fr;
                wf[n] = *(const bf16x8*)&Ws[r * 32 + ((fk ^ ((r >> 1) & 3)) * 8)];
            }
#pragma unroll
            for (int m = 0; m < FM; ++m)
#pragma unroll
                for (int n = 0; n < FN; ++n)
                    acc[m][n] = __builtin_amdgcn_mfma_f32_16x16x32_bf16(
                        af[m], wf[n], acc[m][n], 0, 0, 0);
            __syncthreads();
        }
    }

    const bool dot = p.do_tanh != 0;
#pragma unroll
    for (int n = 0; n < FN; ++n) {
        const int col = col0 + wc * (BN / 2) + n * 16 + fr;
        float b = p.ba[col];
        if (p.bb) b += p.bb[col];
#pragma unroll
        for (int m = 0; m < FM; ++m) {
#pragma unroll
            for (int j = 0; j < 4; ++j) {
                const int r = row0 + wr * (BM / 2) + m * 16 + fk * 4 + j;
                float v = acc[m][n][j] + b;
                if (dot) v = tanhf(v);
                p.C[(size_t)r * p.ldc + col] = v;
                if (p.Cb) p.Cb[(size_t)r * p.ldcb + col] = f2b_rne(v);
            }
        }
    }
}

// GEMM1 (blocks 0..511) + throttled grid-strided cvtB (blocks 512..1023)
__global__ __launch_bounds__(256) void g1cvt_k(GemmP p, CvtArgs ca, unsigned total_n8)
{
    if (blockIdx.x < 512) {
        __shared__ __align__(16) unsigned short As[128 * 32];
        __shared__ __align__(16) unsigned short Ws[64 * 32];
        gemm2p_body<128, 64>(p, blockIdx.x, As, Ws, threadIdx.x);
    } else {
        unsigned i = (blockIdx.x - 512) * 256u + threadIdx.x;
        const unsigned stride = 512u * 256u;          // 131072
        for (unsigned b = 0; b < total_n8; b += stride)
            cvt_do(ca, b + i);
    }
}

// ---------------- row log_softmax (float4-vectorized) -----------------------
__device__ __forceinline__ void logsoftmax_row(float* __restrict__ p, int tid)
{
    const int lane = tid & 63;
    const int wv = tid >> 6;
    __shared__ float redm[4];
    __shared__ float reds[4];

    float4 v[4];
#pragma unroll
    for (int i = 0; i < 4; ++i) v[i] = ((const float4*)p)[i * 256 + tid];

    float m = v[0].x;
#pragma unroll
    for (int i = 0; i < 4; ++i) {
        m = fmaxf(m, fmaxf(fmaxf(v[i].x, v[i].y), fmaxf(v[i].z, v[i].w)));
    }
#pragma unroll
    for (int off = 32; off; off >>= 1) m = fmaxf(m, __shfl_xor(m, off));
    if (lane == 0) redm[wv] = m;
    __syncthreads();
    m = fmaxf(fmaxf(redm[0], redm[1]), fmaxf(redm[2], redm[3]));

    float s = 0.f;
#pragma unroll
    for (int i = 0; i < 4; ++i) {
        s += expf(v[i].x - m); s += expf(v[i].y - m);
        s += expf(v[i].z - m); s += expf(v[i].w - m);
    }
#pragma unroll
    for (int off = 32; off; off >>= 1) s += __shfl_xor(s, off);
    if (lane == 0) reds[wv] = s;
    __syncthreads();
    s = reds[0] + reds[1] + reds[2] + reds[3];

    const float lse = m + logf(s);
#pragma unroll
    for (int i = 0; i < 4; ++i) {
        float4 o;
        o.x = v[i].x - lse; o.y = v[i].y - lse;
        o.z = v[i].z - lse; o.w = v[i].w - lse;
        ((float4*)p)[i * 256 + tid] = o;
    }
}

// GEMM2 at 128x64 (blocks 0..511) + log_softmax rows (512..4607), one dispatch
__global__ __launch_bounds__(256) void g2sm_k(GemmP p, float* __restrict__ logits)
{
    if (blockIdx.x < 512) {
        __shared__ __align__(16) unsigned short As[128 * 32];
        __shared__ __align__(16) unsigned short Ws[64 * 32];
        gemm2p_body<128, 64>(p, blockIdx.x, As, Ws, threadIdx.x);
    } else {
        logsoftmax_row(logits + (size_t)(blockIdx.x - 512) * 4096, threadIdx.x);
    }
}

// ============ per-phase counted 256x256 GEMM (GEMM3) — R10 form (locked) ====
// C = [Aa|Ab] @ [Wa|Wb]^T + bias.  K = 1024+1024, NT = 32 K-tiles of 64.
// LDS: A,B each [2 dbuf][2 half][128 rows][64 k] bf16 (64KB + 64KB).
// Chunk swizzle: LDS chunk cc of row ir holds global k-chunk (cc^ir)&7.
// SCHEDULE (4 phases/tile; stage 1 half/phase in consumption order):
//   p0: vmcnt(4); bar; read af0,wfA(12); stage A0(t+1); MFMA Q00
//   p1: vmcnt(4); bar; read wfB(4);      stage B0(t+1); MFMA Q01
//   p2: vmcnt(4); bar; read af1(8);      stage B1(t+1); MFMA Q11
//   p3: (no bar)                         stage A1(t+1); MFMA Q10
// Tail t=NT-1: waits 4/2/0, no stages. Prologue stages A0,B0,B1,A1 of tile0.

__device__ __forceinline__ void stage_half8(
    const unsigned short* __restrict__ src, int ld, int base_rc, int tau, int h,
    unsigned short* lds, int wid, int lane, bool isA)
{
    unsigned short* dst = lds + (tau & 1) * 16384 + h * 8192 + wid * 1024;
    const int k0 = (tau & 15) << 6;
#pragma unroll
    for (int i = 0; i < 2; ++i) {
        int c = wid * 128 + i * 64 + lane;
        int ir = c >> 3, cc = c & 7;
        int grow = isA ? (base_rc + h * 64 + (ir & 63) + ((ir >> 6) << 7))
                       : (base_rc + h * 32 + (ir & 31) + ((ir >> 5) << 6));
        int gk = k0 + (((cc ^ ir) & 7) << 3);
        gload_lds16(src + (size_t)grow * ld + gk, dst + i * 512);
    }
}

__global__ __launch_bounds__(512, 2) void gemm8p(
    const unsigned short* __restrict__ Aa, const unsigned short* __restrict__ Ab,
    const unsigned short* __restrict__ Wa, const unsigned short* __restrict__ Wb,
    int lda, int ldw, const float* __restrict__ bias,
    float* __restrict__ C, int ldc, int nx)
{
    constexpr int NT = 32;
    __shared__ __align__(16) unsigned short smem[65536];   // 128 KB
    unsigned short* As = smem;
    unsigned short* Bs = smem + 32768;

    int bid = blockIdx.x;
    bid = (bid & 7) * 32 + (bid >> 3);            // XCD swizzle (256 = 8*32)
    const int row0 = (bid / nx) * 256;
    const int col0 = (bid % nx) * 256;

    const int tid = threadIdx.x;
    const int wid = tid >> 6, lane = tid & 63;
    const int wr = wid >> 2, wc = wid & 3;        // 2 x 4 wave grid
    const int fr = lane & 15, fk = lane >> 4;
    const int ch0 = fk ^ (fr & 7);
    const int ch1 = ch0 ^ 4;

#define STA8(tau, h) stage_half8(((tau) < 16 ? Aa : Ab), lda, row0, (tau), (h), As, wid, lane, true)
#define STB8(tau, h) stage_half8(((tau) < 16 ? Wa : Wb), ldw, col0, (tau), (h), Bs, wid, lane, false)

#define LDAF(QM) { const unsigned short* Ap_ = Abase + (QM) * 8192;           \
    _Pragma("unroll") for (int mf = 0; mf < 4; ++mf) {                        \
        int ia = wr * 64 + mf * 16 + fr;                                      \
        af[mf][0] = *(const bf16x8*)&Ap_[ia * 64 + ch0 * 8];                  \
        af[mf][1] = *(const bf16x8*)&Ap_[ia * 64 + ch1 * 8]; } }

#define LDWF(QN, WF) { const unsigned short* Bp_ = Bbase + (QN) * 8192;       \
    _Pragma("unroll") for (int nf = 0; nf < 2; ++nf) {                        \
        int ib = wc * 32 + nf * 16 + fr;                                      \
        WF[nf][0] = *(const bf16x8*)&Bp_[ib * 64 + ch0 * 8];                  \
        WF[nf][1] = *(const bf16x8*)&Bp_[ib * 64 + ch1 * 8]; } }

#define MMQ(QM, QN, WF) {                                                     \
    __builtin_amdgcn_s_setprio(1);                                            \
    _Pragma("unroll") for (int mf = 0; mf < 4; ++mf)                          \
    _Pragma("unroll") for (int nf = 0; nf < 2; ++nf) {                        \
        acc[QM][QN][mf][nf] = __builtin_amdgcn_mfma_f32_16x16x32_bf16(        \
            af[mf][0], WF[nf][0], acc[QM][QN][mf][nf], 0, 0, 0);              \
        acc[QM][QN][mf][nf] = __builtin_amdgcn_mfma_f32_16x16x32_bf16(        \
            af[mf][1], WF[nf][1], acc[QM][QN][mf][nf], 0, 0, 0); }            \
    __builtin_amdgcn_s_setprio(0); }

    f32x4 acc[2][2][4][2] = {};
    bf16x8 af[4][2], wfA[2][2], wfB[2][2];

    // prologue: stage tile0's halves in consumption order A0,B0,B1,A1
    STA8(0, 0); STB8(0, 0); STB8(0, 1); STA8(0, 1);

    for (int t = 0; t < NT; ++t) {
        const unsigned short* Abase = As + (t & 1) * 16384;
        const unsigned short* Bbase = Bs + (t & 1) * 16384;
        const bool more = (t + 1 < NT);

        // p0: Q(0,0) — consumes A0(t),B0(t)
        asm volatile("s_waitcnt vmcnt(4)" ::: "memory");
        __builtin_amdgcn_s_barrier();
        LDAF(0); LDWF(0, wfA);
        if (more) STA8(t + 1, 0);
        MMQ(0, 0, wfA);

        // p1: Q(0,1) — consumes B1(t)
        if (more) { asm volatile("s_waitcnt vmcnt(4)" ::: "memory"); }
        else      { asm volatile("s_waitcnt vmcnt(2)" ::: "memory"); }
        __builtin_amdgcn_s_barrier();
        LDWF(1, wfB);
        if (more) STB8(t + 1, 0);
        MMQ(0, 1, wfB);

        // p2: Q(1,1) — consumes A1(t)
        if (more) { asm volatile("s_waitcnt vmcnt(4)" ::: "memory"); }
        else      { asm volatile("s_waitcnt vmcnt(0)" ::: "memory"); }
        __builtin_amdgcn_s_barrier();
        LDAF(1);
        if (more) STB8(t + 1, 1);
        MMQ(1, 1, wfB);

        // p3: Q(1,0) — zero ds_reads, no barrier
        if (more) STA8(t + 1, 1);
        MMQ(1, 0, wfA);
    }
#undef MMQ
#undef LDAF
#undef LDWF
#undef STA8
#undef STB8

    // epilogue: acc -> LDS (fp32, +bias, XOR de-conflict) -> float4 stores.
    // C/D frag layout: col = lane&15, row = (lane>>4)*4 + j.
    float bv[2][2];
#pragma unroll
    for (int qn = 0; qn < 2; ++qn)
#pragma unroll
        for (int nf = 0; nf < 2; ++nf)
            bv[qn][nf] = bias[col0 + wc * 64 + qn * 32 + nf * 16 + fr];

    float* Ct = (float*)smem;                     // [128][256] fp32 = 128KB
    __syncthreads();                              // all LDS GEMM traffic done
#pragma unroll
    for (int qm = 0; qm < 2; ++qm) {
        if (qm) __syncthreads();
#pragma unroll
        for (int qn = 0; qn < 2; ++qn)
#pragma unroll
            for (int nf = 0; nf < 2; ++nf) {
                const int col = wc * 64 + qn * 32 + nf * 16 + fr;
#pragma unroll
                for (int mf = 0; mf < 4; ++mf)
#pragma unroll
                    for (int j = 0; j < 4; ++j) {
                        int lr = wr * 64 + mf * 16 + fk * 4 + j;
                        int pc = col ^ (((lr >> 2) & 3) << 4);
                        Ct[lr * 256 + pc] = acc[qm][qn][mf][nf][j] + bv[qn][nf];
                    }
            }
        __syncthreads();
#pragma unroll
        for (int k = 0; k < 16; ++k) {
            int idx = k * 512 + tid;
            int lrow = idx >> 6, c4 = idx & 63;
            int pc4 = (c4 * 4) ^ (((lrow >> 2) & 3) << 4);
            int grow = row0 + qm * 64 + (lrow & 63) + ((lrow >> 6) << 7);
            *(float4*)&C[(size_t)grow * ldc + col0 + c4 * 4] =
                *(const float4*)&Ct[lrow * 256 + pc4];
        }
    }
}

// ============================================================================
extern "C" void kernel_launch(void* const* d_in, const int* in_sizes, int n_in,
                              void* d_out, int out_size, void* d_ws, size_t ws_size,
                              hipStream_t stream)
{
    (void)in_sizes; (void)n_in; (void)out_size; (void)ws_size;

    const float* input  = (const float*)d_in[0];
    const float* hidden = (const float*)d_in[1];
    const float* b_ih0  = (const float*)d_in[4];
    const float* b_hh0  = (const float*)d_in[5];
    const float* b_ih1  = (const float*)d_in[8];
    const float* b_hh1  = (const float*)d_in[9];
    const float* b_out  = (const float*)d_in[11];

    float* out = (float*)d_out;                    // [4096,4096]
    float* h0  = out + (size_t)4096 * 4096;
    float* h1  = h0 + (size_t)4096 * 1024;

    unsigned short* xb    = (unsigned short*)d_ws;
    unsigned short* hidb  = xb    + (size_t)4096 * 1024;
    unsigned short* h0b   = hidb  + (size_t)2 * 4096 * 1024;
    unsigned short* Wih0b = h0b   + (size_t)4096 * 1024;
    unsigned short* Whh0b = Wih0b + (size_t)1024 * 1024;
    unsigned short* Wih1b = Whh0b + (size_t)1024 * 1024;
    unsigned short* Whh1b = Wih1b + (size_t)1024 * 1024;
    unsigned short* Woutb = Whh1b + (size_t)1024 * 1024;
    unsigned short* hid0b = hidb;
    unsigned short* hid1b = hidb + (size_t)4096 * 1024;

    // f2bA: only GEMM1's inputs (x, hid0, W_ih0, W_hh0) — 5120 blocks
    CvtArgs ca1;
    ca1.seg[0] = { input,                 xb,    524288u };
    ca1.seg[1] = { hidden,                hid0b, 524288u };
    ca1.seg[2] = { (const float*)d_in[2], Wih0b, 131072u };
    ca1.seg[3] = { (const float*)d_in[3], Whh0b, 131072u };
    hipLaunchKernelGGL(f2b_multi, dim3(5120), dim3(256), 0, stream, ca1);

    // GEMM1 (512 blocks) + throttled cvtB (512 grid-strided blocks)
    GemmP p1;
    p1.Aa = xb;    p1.Ab = hid0b; p1.lda = 1024;
    p1.Wa = Wih0b; p1.Wb = Whh0b; p1.ldw = 1024;
    p1.ba = b_ih0; p1.bb = b_hh0;
    p1.C = h0; p1.ldc = 1024; p1.Cb = h0b; p1.ldcb = 1024;
    p1.nx = 16; p1.nb = 512; p1.do_tanh = 1;
    CvtArgs ca2;
    ca2.seg[0] = { hidden + (size_t)4096 * 1024, hid1b, 524288u };
    ca2.seg[1] = { (const float*)d_in[6],  Wih1b, 131072u };
    ca2.seg[2] = { (const float*)d_in[7],  Whh1b, 131072u };
    ca2.seg[3] = { (const float*)d_in[10], Woutb, 1048576u };
    hipLaunchKernelGGL(g1cvt_k, dim3(1024), dim3(256), 0, stream,
                       p1, ca2, 1835008u);

    // GEMM3: logits = x@W_out[:,:1024]^T + h0@W_out[:,1024:]^T + b_out
    hipLaunchKernelGGL(gemm8p, dim3(256), dim3(512), 0, stream,
                       xb, h0b, Woutb, Woutb + 1024, 1024, 2048,
                       b_out, out, 4096, 16);

    // GEMM2 at 128x64 (512 blocks) + log_softmax (4096 rows), one dispatch
    GemmP p2;
    p2.Aa = h0b;   p2.Ab = hid1b; p2.lda = 1024;
    p2.Wa = Wih1b; p2.Wb = Whh1b; p2.ldw = 1024;
    p2.ba = b_ih1; p2.bb = b_hh1;
    p2.C = h1; p2.ldc = 1024; p2.Cb = nullptr; p2.ldcb = 0;
    p2.nx = 16; p2.nb = 512; p2.do_tanh = 1;
    hipLaunchKernelGGL(g2sm_k, dim3(4608), dim3(256), 0, stream, p2, out);
}

// Round 13
// 170.670 us; speedup vs baseline: 1.2192x; 1.2192x over previous
//
#include <hip/hip_runtime.h>
#include <math.h>

// ---------------------------------------------------------------------------
// RNN_6451040879094  (B=4096, I=H=1024, O=4096, fp32 in/out)
// R13: REVERT to R10 launch structure (best, 170.5us):
//        f2b (8-seg, 12288 blk) -> gemm1_k (512 blk) -> gemm8p (R10 form,
//        locked) -> g2sm (GEMM2@128x64 + softmax).
//      NEW: bf16 logits path (ws_size-gated): gemm8p epilogue emits bf16
//        logits into d_ws (store 64->32MB); softmax reads bf16 (read 64->32MB)
//        and writes fp32 out. Fallback = exact R10 fp32 in-place path.
// d_out: out(4096*4096) ++ h0(4096*1024) ++ h1(4096*1024), fp32.
// ---------------------------------------------------------------------------

typedef __attribute__((ext_vector_type(8))) short bf16x8;
typedef __attribute__((ext_vector_type(4))) float f32x4;

__device__ __forceinline__ unsigned short f2b_rne(float f) {
    unsigned int x = __float_as_uint(f);
    x += 0x7FFF + ((x >> 16) & 1);
    return (unsigned short)(x >> 16);
}

__device__ __forceinline__ void gload_lds16(const void* g, void* l) {
    __builtin_amdgcn_global_load_lds(
        (const __attribute__((address_space(1))) void*)g,
        (__attribute__((address_space(3))) void*)l,
        16, 0, 0);
}

// ---------------- fp32 -> bf16 conversion (8 segments) ----------------------
struct CvtSeg { const float* src; unsigned short* dst; unsigned n8; };
struct CvtArgs { CvtSeg seg[8]; };

__global__ __launch_bounds__(256) void f2b_multi(CvtArgs a)
{
    unsigned i = blockIdx.x * 256u + threadIdx.x;
#pragma unroll
    for (int s = 0; s < 8; ++s) {
        if (i < a.seg[s].n8) {
            const float4* src = (const float4*)a.seg[s].src;
            float4 u = src[2 * (size_t)i];
            float4 v = src[2 * (size_t)i + 1];
            unsigned short t[8] = {
                f2b_rne(u.x), f2b_rne(u.y), f2b_rne(u.z), f2b_rne(u.w),
                f2b_rne(v.x), f2b_rne(v.y), f2b_rne(v.z), f2b_rne(v.w)};
            *(uint4*)(a.seg[s].dst + 8 * (size_t)i) = *(const uint4*)t;
            return;
        }
        i -= a.seg[s].n8;
    }
}

// ================= 2-phase 128xBN GEMM (GEMM1 / GEMM2 roles) ================
struct GemmP {
    const unsigned short *Aa, *Ab; int lda;
    const unsigned short *Wa, *Wb; int ldw;
    const float *ba, *bb;
    float* C; int ldc;
    unsigned short* Cb; int ldcb;
    int nx, nb, do_tanh;
};

template<int BM, int BN>
__device__ __forceinline__ void gemm2p_body(
    const GemmP& p, int bid0, unsigned short* As, unsigned short* Ws, int tid)
{
    constexpr int FM = BM / 32;
    constexpr int FN = BN / 32;
    int bid = (bid0 & 7) * (p.nb >> 3) + (bid0 >> 3);
    const int row0 = (bid / p.nx) * BM;
    const int col0 = (bid % p.nx) * BN;

    const int wid = tid >> 6, lane = tid & 63;
    const int wr = wid >> 1, wc = wid & 1;
    const int fr = lane & 15, fk = lane >> 4;

    f32x4 acc[FM][FN] = {};

    for (int h = 0; h < 2; ++h) {
        const unsigned short* A = h ? p.Ab : p.Aa;
        const unsigned short* W = h ? p.Wb : p.Wa;
        for (int k0 = 0; k0 < 1024; k0 += 32) {
#pragma unroll
            for (int i = 0; i < BM / 64; ++i) {
                int c = i * 256 + wid * 64 + lane;
                int r = c >> 2, ol = c & 3;
                int os = ol ^ ((r >> 1) & 3);
                gload_lds16(A + (size_t)(row0 + r) * p.lda + k0 + os * 8,
                            As + (i * 256 + wid * 64) * 8);
            }
#pragma unroll
            for (int i = 0; i < BN / 64; ++i) {
                int c = i * 256 + wid * 64 + lane;
                int r = c >> 2, ol = c & 3;
                int os = ol ^ ((r >> 1) & 3);
                gload_lds16(W + (size_t)(col0 + r) * p.ldw + k0 + os * 8,
                            Ws + (i * 256 + wid * 64) * 8);
            }
            __syncthreads();

            bf16x8 af[FM], wf[FN];
#pragma unroll
            for (int m = 0; m < FM; ++m) {
                int r = wr * (BM / 2) + m * 16 + fr;
                af[m] = *(const bf16x8*)&As[r * 32 + ((fk ^ ((r >> 1) & 3)) * 8)];
            }
#pragma unroll
            for (int n = 0; n < FN; ++n) {
                int r = wc * (BN / 2) + n * 16 + fr;
                wf[n] = *(const bf16x8*)&Ws[r * 32 + ((fk ^ ((r >> 1) & 3)) * 8)];
            }
#pragma unroll
            for (int m = 0; m < FM; ++m)
#pragma unroll
                for (int n = 0; n < FN; ++n)
                    acc[m][n] = __builtin_amdgcn_mfma_f32_16x16x32_bf16(
                        af[m], wf[n], acc[m][n], 0, 0, 0);
            __syncthreads();
        }
    }

    const bool dot = p.do_tanh != 0;
#pragma unroll
    for (int n = 0; n < FN; ++n) {
        const int col = col0 + wc * (BN / 2) + n * 16 + fr;
        float b = p.ba[col];
        if (p.bb) b += p.bb[col];
#pragma unroll
        for (int m = 0; m < FM; ++m) {
#pragma unroll
            for (int j = 0; j < 4; ++j) {
                const int r = row0 + wr * (BM / 2) + m * 16 + fk * 4 + j;
                float v = acc[m][n][j] + b;
                if (dot) v = tanhf(v);
                p.C[(size_t)r * p.ldc + col] = v;
                if (p.Cb) p.Cb[(size_t)r * p.ldcb + col] = f2b_rne(v);
            }
        }
    }
}

__global__ __launch_bounds__(256) void gemm1_k(GemmP p)
{
    __shared__ __align__(16) unsigned short As[128 * 32];
    __shared__ __align__(16) unsigned short Ws[64 * 32];
    gemm2p_body<128, 64>(p, blockIdx.x, As, Ws, threadIdx.x);
}

// ---------------- row log_softmax variants ----------------------------------
// fp32 in-place (fallback path)
__device__ __forceinline__ void logsoftmax_row_f32(float* __restrict__ p, int tid)
{
    const int lane = tid & 63;
    const int wv = tid >> 6;
    __shared__ float redm[4];
    __shared__ float reds[4];

    float4 v[4];
#pragma unroll
    for (int i = 0; i < 4; ++i) v[i] = ((const float4*)p)[i * 256 + tid];

    float m = v[0].x;
#pragma unroll
    for (int i = 0; i < 4; ++i)
        m = fmaxf(m, fmaxf(fmaxf(v[i].x, v[i].y), fmaxf(v[i].z, v[i].w)));
#pragma unroll
    for (int off = 32; off; off >>= 1) m = fmaxf(m, __shfl_xor(m, off));
    if (lane == 0) redm[wv] = m;
    __syncthreads();
    m = fmaxf(fmaxf(redm[0], redm[1]), fmaxf(redm[2], redm[3]));

    float s = 0.f;
#pragma unroll
    for (int i = 0; i < 4; ++i) {
        s += expf(v[i].x - m); s += expf(v[i].y - m);
        s += expf(v[i].z - m); s += expf(v[i].w - m);
    }
#pragma unroll
    for (int off = 32; off; off >>= 1) s += __shfl_xor(s, off);
    if (lane == 0) reds[wv] = s;
    __syncthreads();
    s = reds[0] + reds[1] + reds[2] + reds[3];

    const float lse = m + logf(s);
#pragma unroll
    for (int i = 0; i < 4; ++i) {
        float4 o;
        o.x = v[i].x - lse; o.y = v[i].y - lse;
        o.z = v[i].z - lse; o.w = v[i].w - lse;
        ((float4*)p)[i * 256 + tid] = o;
    }
}

// bf16-in, fp32-out
__device__ __forceinline__ void logsoftmax_row_b16(
    const unsigned short* __restrict__ lb, float* __restrict__ op, int tid)
{
    const int lane = tid & 63;
    const int wv = tid >> 6;
    __shared__ float redm[4];
    __shared__ float reds[4];

    uint4 r[2];
    r[0] = *(const uint4*)&lb[tid * 8];
    r[1] = *(const uint4*)&lb[2048 + tid * 8];
    float v[16];
#pragma unroll
    for (int h = 0; h < 2; ++h)
#pragma unroll
        for (int j = 0; j < 4; ++j) {
            unsigned u = ((const unsigned*)&r[h])[j];
            v[h * 8 + 2 * j]     = __uint_as_float(u << 16);
            v[h * 8 + 2 * j + 1] = __uint_as_float(u & 0xFFFF0000u);
        }

    float m = v[0];
#pragma unroll
    for (int i = 1; i < 16; ++i) m = fmaxf(m, v[i]);
#pragma unroll
    for (int off = 32; off; off >>= 1) m = fmaxf(m, __shfl_xor(m, off));
    if (lane == 0) redm[wv] = m;
    __syncthreads();
    m = fmaxf(fmaxf(redm[0], redm[1]), fmaxf(redm[2], redm[3]));

    float s = 0.f;
#pragma unroll
    for (int i = 0; i < 16; ++i) s += expf(v[i] - m);
#pragma unroll
    for (int off = 32; off; off >>= 1) s += __shfl_xor(s, off);
    if (lane == 0) reds[wv] = s;
    __syncthreads();
    s = reds[0] + reds[1] + reds[2] + reds[3];

    const float lse = m + logf(s);
#pragma unroll
    for (int h = 0; h < 2; ++h) {
        float4 o0, o1;
        o0.x = v[h*8+0]-lse; o0.y = v[h*8+1]-lse; o0.z = v[h*8+2]-lse; o0.w = v[h*8+3]-lse;
        o1.x = v[h*8+4]-lse; o1.y = v[h*8+5]-lse; o1.z = v[h*8+6]-lse; o1.w = v[h*8+7]-lse;
        *(float4*)&op[h * 2048 + tid * 8]     = o0;
        *(float4*)&op[h * 2048 + tid * 8 + 4] = o1;
    }
}

// GEMM2 at 128x64 (blocks 0..511) + log_softmax rows (512..4607), one dispatch
template<bool B16>
__global__ __launch_bounds__(256) void g2sm_k(
    GemmP p, float* __restrict__ out, const unsigned short* __restrict__ lb16)
{
    if (blockIdx.x < 512) {
        __shared__ __align__(16) unsigned short As[128 * 32];
        __shared__ __align__(16) unsigned short Ws[64 * 32];
        gemm2p_body<128, 64>(p, blockIdx.x, As, Ws, threadIdx.x);
    } else {
        const int row = blockIdx.x - 512;
        if (B16)
            logsoftmax_row_b16(lb16 + (size_t)row * 4096,
                               out + (size_t)row * 4096, threadIdx.x);
        else
            logsoftmax_row_f32(out + (size_t)row * 4096, threadIdx.x);
    }
}

// ============ per-phase counted 256x256 GEMM (GEMM3) — R10 form (locked) ====
// Schedule: p0 vmcnt(4);bar;rd af0,wfA;st A0(t+1);Q00 | p1 ...B1(t)... |
// p2 ...A1(t)... | p3 no-bar st A1(t+1) Q10. Tail 4/2/0. See R10 notes.

__device__ __forceinline__ void stage_half8(
    const unsigned short* __restrict__ src, int ld, int base_rc, int tau, int h,
    unsigned short* lds, int wid, int lane, bool isA)
{
    unsigned short* dst = lds + (tau & 1) * 16384 + h * 8192 + wid * 1024;
    const int k0 = (tau & 15) << 6;
#pragma unroll
    for (int i = 0; i < 2; ++i) {
        int c = wid * 128 + i * 64 + lane;
        int ir = c >> 3, cc = c & 7;
        int grow = isA ? (base_rc + h * 64 + (ir & 63) + ((ir >> 6) << 7))
                       : (base_rc + h * 32 + (ir & 31) + ((ir >> 5) << 6));
        int gk = k0 + (((cc ^ ir) & 7) << 3);
        gload_lds16(src + (size_t)grow * ld + gk, dst + i * 512);
    }
}

template<bool B16OUT>
__global__ __launch_bounds__(512, 2) void gemm8p(
    const unsigned short* __restrict__ Aa, const unsigned short* __restrict__ Ab,
    const unsigned short* __restrict__ Wa, const unsigned short* __restrict__ Wb,
    int lda, int ldw, const float* __restrict__ bias,
    float* __restrict__ C, unsigned short* __restrict__ Cb16, int ldc, int nx)
{
    constexpr int NT = 32;
    __shared__ __align__(16) unsigned short smem[65536];   // 128 KB
    unsigned short* As = smem;
    unsigned short* Bs = smem + 32768;

    int bid = blockIdx.x;
    bid = (bid & 7) * 32 + (bid >> 3);            // XCD swizzle (256 = 8*32)
    const int row0 = (bid / nx) * 256;
    const int col0 = (bid % nx) * 256;

    const int tid = threadIdx.x;
    const int wid = tid >> 6, lane = tid & 63;
    const int wr = wid >> 2, wc = wid & 3;        // 2 x 4 wave grid
    const int fr = lane & 15, fk = lane >> 4;
    const int ch0 = fk ^ (fr & 7);
    const int ch1 = ch0 ^ 4;

#define STA8(tau, h) stage_half8(((tau) < 16 ? Aa : Ab), lda, row0, (tau), (h), As, wid, lane, true)
#define STB8(tau, h) stage_half8(((tau) < 16 ? Wa : Wb), ldw, col0, (tau), (h), Bs, wid, lane, false)

#define LDAF(QM) { const unsigned short* Ap_ = Abase + (QM) * 8192;           \
    _Pragma("unroll") for (int mf = 0; mf < 4; ++mf) {                        \
        int ia = wr * 64 + mf * 16 + fr;                                      \
        af[mf][0] = *(const bf16x8*)&Ap_[ia * 64 + ch0 * 8];                  \
        af[mf][1] = *(const bf16x8*)&Ap_[ia * 64 + ch1 * 8]; } }

#define LDWF(QN, WF) { const unsigned short* Bp_ = Bbase + (QN) * 8192;       \
    _Pragma("unroll") for (int nf = 0; nf < 2; ++nf) {                        \
        int ib = wc * 32 + nf * 16 + fr;                                      \
        WF[nf][0] = *(const bf16x8*)&Bp_[ib * 64 + ch0 * 8];                  \
        WF[nf][1] = *(const bf16x8*)&Bp_[ib * 64 + ch1 * 8]; } }

#define MMQ(QM, QN, WF) {                                                     \
    __builtin_amdgcn_s_setprio(1);                                            \
    _Pragma("unroll") for (int mf = 0; mf < 4; ++mf)                          \
    _Pragma("unroll") for (int nf = 0; nf < 2; ++nf) {                        \
        acc[QM][QN][mf][nf] = __builtin_amdgcn_mfma_f32_16x16x32_bf16(        \
            af[mf][0], WF[nf][0], acc[QM][QN][mf][nf], 0, 0, 0);              \
        acc[QM][QN][mf][nf] = __builtin_amdgcn_mfma_f32_16x16x32_bf16(        \
            af[mf][1], WF[nf][1], acc[QM][QN][mf][nf], 0, 0, 0); }            \
    __builtin_amdgcn_s_setprio(0); }

    f32x4 acc[2][2][4][2] = {};
    bf16x8 af[4][2], wfA[2][2], wfB[2][2];

    // prologue: stage tile0's halves in consumption order A0,B0,B1,A1
    STA8(0, 0); STB8(0, 0); STB8(0, 1); STA8(0, 1);

    for (int t = 0; t < NT; ++t) {
        const unsigned short* Abase = As + (t & 1) * 16384;
        const unsigned short* Bbase = Bs + (t & 1) * 16384;
        const bool more = (t + 1 < NT);

        // p0: Q(0,0) — consumes A0(t),B0(t)
        asm volatile("s_waitcnt vmcnt(4)" ::: "memory");
        __builtin_amdgcn_s_barrier();
        LDAF(0); LDWF(0, wfA);
        if (more) STA8(t + 1, 0);
        MMQ(0, 0, wfA);

        // p1: Q(0,1) — consumes B1(t)
        if (more) { asm volatile("s_waitcnt vmcnt(4)" ::: "memory"); }
        else      { asm volatile("s_waitcnt vmcnt(2)" ::: "memory"); }
        __builtin_amdgcn_s_barrier();
        LDWF(1, wfB);
        if (more) STB8(t + 1, 0);
        MMQ(0, 1, wfB);

        // p2: Q(1,1) — consumes A1(t)
        if (more) { asm volatile("s_waitcnt vmcnt(4)" ::: "memory"); }
        else      { asm volatile("s_waitcnt vmcnt(0)" ::: "memory"); }
        __builtin_amdgcn_s_barrier();
        LDAF(1);
        if (more) STB8(t + 1, 1);
        MMQ(1, 1, wfB);

        // p3: Q(1,0) — zero ds_reads, no barrier
        if (more) STA8(t + 1, 1);
        MMQ(1, 0, wfA);
    }
#undef MMQ
#undef LDAF
#undef LDWF
#undef STA8
#undef STB8

    // epilogue: acc -> LDS (fp32, +bias, XOR de-conflict) -> coalesced stores
    // (float4 fp32 or ushort4 bf16). C/D layout: col=lane&15, row=(lane>>4)*4+j.
    float bv[2][2];
#pragma unroll
    for (int qn = 0; qn < 2; ++qn)
#pragma unroll
        for (int nf = 0; nf < 2; ++nf)
            bv[qn][nf] = bias[col0 + wc * 64 + qn * 32 + nf * 16 + fr];

    float* Ct = (float*)smem;                     // [128][256] fp32 = 128KB
    __syncthreads();
#pragma unroll
    for (int qm = 0; qm < 2; ++qm) {
        if (qm) __syncthreads();
#pragma unroll
        for (int qn = 0; qn < 2; ++qn)
#pragma unroll
            for (int nf = 0; nf < 2; ++nf) {
                const int col = wc * 64 + qn * 32 + nf * 16 + fr;
#pragma unroll
                for (int mf = 0; mf < 4; ++mf)
#pragma unroll
                    for (int j = 0; j < 4; ++j) {
                        int lr = wr * 64 + mf * 16 + fk * 4 + j;
                        int pc = col ^ (((lr >> 2) & 3) << 4);
                        Ct[lr * 256 + pc] = acc[qm][qn][mf][nf][j] + bv[qn][nf];
                    }
            }
        __syncthreads();
#pragma unroll
        for (int k = 0; k < 16; ++k) {
            int idx = k * 512 + tid;
            int lrow = idx >> 6, c4 = idx & 63;
            int pc4 = (c4 * 4) ^ (((lrow >> 2) & 3) << 4);
            int grow = row0 + qm * 64 + (lrow & 63) + ((lrow >> 6) << 7);
            float4 v = *(const float4*)&Ct[lrow * 256 + pc4];
            if (B16OUT) {
                unsigned short o[4] = { f2b_rne(v.x), f2b_rne(v.y),
                                        f2b_rne(v.z), f2b_rne(v.w) };
                *(ushort4*)&Cb16[(size_t)grow * ldc + col0 + c4 * 4] =
                    *(const ushort4*)o;
            } else {
                *(float4*)&C[(size_t)grow * ldc + col0 + c4 * 4] = v;
            }
        }
    }
}

// ============================================================================
extern "C" void kernel_launch(void* const* d_in, const int* in_sizes, int n_in,
                              void* d_out, int out_size, void* d_ws, size_t ws_size,
                              hipStream_t stream)
{
    (void)in_sizes; (void)n_in; (void)out_size;

    const float* input  = (const float*)d_in[0];
    const float* hidden = (const float*)d_in[1];
    const float* b_ih0  = (const float*)d_in[4];
    const float* b_hh0  = (const float*)d_in[5];
    const float* b_ih1  = (const float*)d_in[8];
    const float* b_hh1  = (const float*)d_in[9];
    const float* b_out  = (const float*)d_in[11];

    float* out = (float*)d_out;                    // [4096,4096]
    float* h0  = out + (size_t)4096 * 4096;
    float* h1  = h0 + (size_t)4096 * 1024;

    unsigned short* xb    = (unsigned short*)d_ws;
    unsigned short* hidb  = xb    + (size_t)4096 * 1024;
    unsigned short* h0b   = hidb  + (size_t)2 * 4096 * 1024;
    unsigned short* Wih0b = h0b   + (size_t)4096 * 1024;
    unsigned short* Whh0b = Wih0b + (size_t)1024 * 1024;
    unsigned short* Wih1b = Whh0b + (size_t)1024 * 1024;
    unsigned short* Whh1b = Wih1b + (size_t)1024 * 1024;
    unsigned short* Woutb = Whh1b + (size_t)1024 * 1024;
    unsigned short* lb16  = Woutb + (size_t)4096 * 2048;   // bf16 logits, 32MB
    unsigned short* hid0b = hidb;
    unsigned short* hid1b = hidb + (size_t)4096 * 1024;

    // bf16-logits path needs 44M ushorts = 92274688 B of workspace
    const bool useB16 = ws_size >= 92274688ull;

    // one standalone conversion pass (R10)
    CvtArgs ca;
    ca.seg[0] = { input,                 xb,    524288u };
    ca.seg[1] = { hidden,                hidb, 1048576u };
    ca.seg[2] = { (const float*)d_in[2], Wih0b, 131072u };
    ca.seg[3] = { (const float*)d_in[3], Whh0b, 131072u };
    ca.seg[4] = { (const float*)d_in[6], Wih1b, 131072u };
    ca.seg[5] = { (const float*)d_in[7], Whh1b, 131072u };
    ca.seg[6] = { (const float*)d_in[10],Woutb, 1048576u };
    ca.seg[7] = { nullptr, nullptr, 0u };
    hipLaunchKernelGGL(f2b_multi, dim3(12288), dim3(256), 0, stream, ca);

    // GEMM1: h0 = tanh(x@Wih0^T + hid0@Whh0^T + b), 128x64 tiles, 512 blocks
    GemmP p1;
    p1.Aa = xb;    p1.Ab = hid0b; p1.lda = 1024;
    p1.Wa = Wih0b; p1.Wb = Whh0b; p1.ldw = 1024;
    p1.ba = b_ih0; p1.bb = b_hh0;
    p1.C = h0; p1.ldc = 1024; p1.Cb = h0b; p1.ldcb = 1024;
    p1.nx = 16; p1.nb = 512; p1.do_tanh = 1;
    hipLaunchKernelGGL(gemm1_k, dim3(512), dim3(256), 0, stream, p1);

    // GEMM3: logits = x@W_out[:,:1024]^T + h0@W_out[:,1024:]^T + b_out
    if (useB16) {
        hipLaunchKernelGGL((gemm8p<true>), dim3(256), dim3(512), 0, stream,
                           xb, h0b, Woutb, Woutb + 1024, 1024, 2048,
                           b_out, out, lb16, 4096, 16);
    } else {
        hipLaunchKernelGGL((gemm8p<false>), dim3(256), dim3(512), 0, stream,
                           xb, h0b, Woutb, Woutb + 1024, 1024, 2048,
                           b_out, out, lb16, 4096, 16);
    }

    // GEMM2 at 128x64 (512 blocks) + log_softmax (4096 rows), one dispatch
    GemmP p2;
    p2.Aa = h0b;   p2.Ab = hid1b; p2.lda = 1024;
    p2.Wa = Wih1b; p2.Wb = Whh1b; p2.ldw = 1024;
    p2.ba = b_ih1; p2.bb = b_hh1;
    p2.C = h1; p2.ldc = 1024; p2.Cb = nullptr; p2.ldcb = 0;
    p2.nx = 16; p2.nb = 512; p2.do_tanh = 1;
    if (useB16) {
        hipLaunchKernelGGL((g2sm_k<true>), dim3(4608), dim3(256), 0, stream,
                           p2, out, lb16);
    } else {
        hipLaunchKernelGGL((g2sm_k<false>), dim3(4608), dim3(256), 0, stream,
                           p2, out, lb16);
    }
}

// Round 14
// 162.198 us; speedup vs baseline: 1.2829x; 1.0522x over previous
//
#include <hip/hip_runtime.h>
#include <math.h>

// ---------------------------------------------------------------------------
// RNN_6451040879094  (B=4096, I=H=1024, O=4096, fp32 in/out)
// R14: 2-phase GEMM bodies (gemm1, G2) move to BK=64: LDS [BM][64] (24KB),
//      half the barriers (32 vs 64 per K=2048), 8-chunk stage swizzle
//      cc^(r&7) (same involution as gemm8p's stage_half8). Volume/MFMA
//      unchanged. gemm8p locked at R13 form (bf16 logits). Softmax bf16-in.
// d_out: out(4096*4096) ++ h0(4096*1024) ++ h1(4096*1024), fp32.
// ---------------------------------------------------------------------------

typedef __attribute__((ext_vector_type(8))) short bf16x8;
typedef __attribute__((ext_vector_type(4))) float f32x4;

__device__ __forceinline__ unsigned short f2b_rne(float f) {
    unsigned int x = __float_as_uint(f);
    x += 0x7FFF + ((x >> 16) & 1);
    return (unsigned short)(x >> 16);
}

__device__ __forceinline__ void gload_lds16(const void* g, void* l) {
    __builtin_amdgcn_global_load_lds(
        (const __attribute__((address_space(1))) void*)g,
        (__attribute__((address_space(3))) void*)l,
        16, 0, 0);
}

// ---------------- fp32 -> bf16 conversion (8 segments) ----------------------
struct CvtSeg { const float* src; unsigned short* dst; unsigned n8; };
struct CvtArgs { CvtSeg seg[8]; };

__global__ __launch_bounds__(256) void f2b_multi(CvtArgs a)
{
    unsigned i = blockIdx.x * 256u + threadIdx.x;
#pragma unroll
    for (int s = 0; s < 8; ++s) {
        if (i < a.seg[s].n8) {
            const float4* src = (const float4*)a.seg[s].src;
            float4 u = src[2 * (size_t)i];
            float4 v = src[2 * (size_t)i + 1];
            unsigned short t[8] = {
                f2b_rne(u.x), f2b_rne(u.y), f2b_rne(u.z), f2b_rne(u.w),
                f2b_rne(v.x), f2b_rne(v.y), f2b_rne(v.z), f2b_rne(v.w)};
            *(uint4*)(a.seg[s].dst + 8 * (size_t)i) = *(const uint4*)t;
            return;
        }
        i -= a.seg[s].n8;
    }
}

// ================= 2-phase BK=64 GEMM body (GEMM1 / GEMM2 roles) ============
// LDS: As[BM][64], Ws[BN][64] bf16; chunk swizzle: LDS chunk cc of row r
// holds global k-chunk (cc^r)&7. Frag read: k-group fk at chunk fk^(r&7),
// kk=1 at ^4. 32 K-steps (barrier pairs) for K=2048 vs 64 at BK=32.
struct GemmP {
    const unsigned short *Aa, *Ab; int lda;
    const unsigned short *Wa, *Wb; int ldw;
    const float *ba, *bb;
    float* C; int ldc;
    unsigned short* Cb; int ldcb;
    int nx, nb, do_tanh;
};

template<int BM, int BN>
__device__ __forceinline__ void gemm2p_body(
    const GemmP& p, int bid0, unsigned short* As, unsigned short* Ws, int tid)
{
    constexpr int FM = BM / 32;
    constexpr int FN = BN / 32;
    int bid = (bid0 & 7) * (p.nb >> 3) + (bid0 >> 3);
    const int row0 = (bid / p.nx) * BM;
    const int col0 = (bid % p.nx) * BN;

    const int wid = tid >> 6, lane = tid & 63;
    const int wr = wid >> 1, wc = wid & 1;
    const int fr = lane & 15, fk = lane >> 4;

    f32x4 acc[FM][FN] = {};

    for (int h = 0; h < 2; ++h) {
        const unsigned short* A = h ? p.Ab : p.Aa;
        const unsigned short* W = h ? p.Wb : p.Wa;
        for (int k0 = 0; k0 < 1024; k0 += 64) {
            // stage: BM*8 chunks of 16B for A, BN*8 for W; lane c=i*256+wid*64+lane
#pragma unroll
            for (int i = 0; i < BM / 32; ++i) {
                int c = i * 256 + wid * 64 + lane;
                int r = c >> 3, cc = c & 7;
                int gk = k0 + (((cc ^ r) & 7) << 3);
                gload_lds16(A + (size_t)(row0 + r) * p.lda + gk,
                            As + (i * 256 + wid * 64) * 8);
            }
#pragma unroll
            for (int i = 0; i < BN / 32; ++i) {
                int c = i * 256 + wid * 64 + lane;
                int r = c >> 3, cc = c & 7;
                int gk = k0 + (((cc ^ r) & 7) << 3);
                gload_lds16(W + (size_t)(col0 + r) * p.ldw + gk,
                            Ws + (i * 256 + wid * 64) * 8);
            }
            __syncthreads();   // full vmcnt(0)+lgkmcnt(0) drain + barrier

            bf16x8 af[FM][2], wf[FN][2];
#pragma unroll
            for (int m = 0; m < FM; ++m) {
                int r = wr * (BM / 2) + m * 16 + fr;
                int cc = fk ^ (r & 7);
                af[m][0] = *(const bf16x8*)&As[r * 64 + cc * 8];
                af[m][1] = *(const bf16x8*)&As[r * 64 + (cc ^ 4) * 8];
            }
#pragma unroll
            for (int n = 0; n < FN; ++n) {
                int r = wc * (BN / 2) + n * 16 + fr;
                int cc = fk ^ (r & 7);
                wf[n][0] = *(const bf16x8*)&Ws[r * 64 + cc * 8];
                wf[n][1] = *(const bf16x8*)&Ws[r * 64 + (cc ^ 4) * 8];
            }
#pragma unroll
            for (int m = 0; m < FM; ++m)
#pragma unroll
                for (int n = 0; n < FN; ++n) {
                    acc[m][n] = __builtin_amdgcn_mfma_f32_16x16x32_bf16(
                        af[m][0], wf[n][0], acc[m][n], 0, 0, 0);
                    acc[m][n] = __builtin_amdgcn_mfma_f32_16x16x32_bf16(
                        af[m][1], wf[n][1], acc[m][n], 0, 0, 0);
                }
            __syncthreads();
        }
    }

    const bool dot = p.do_tanh != 0;
#pragma unroll
    for (int n = 0; n < FN; ++n) {
        const int col = col0 + wc * (BN / 2) + n * 16 + fr;
        float b = p.ba[col];
        if (p.bb) b += p.bb[col];
#pragma unroll
        for (int m = 0; m < FM; ++m) {
#pragma unroll
            for (int j = 0; j < 4; ++j) {
                const int r = row0 + wr * (BM / 2) + m * 16 + fk * 4 + j;
                float v = acc[m][n][j] + b;
                if (dot) v = tanhf(v);
                p.C[(size_t)r * p.ldc + col] = v;
                if (p.Cb) p.Cb[(size_t)r * p.ldcb + col] = f2b_rne(v);
            }
        }
    }
}

__global__ __launch_bounds__(256) void gemm1_k(GemmP p)
{
    __shared__ __align__(16) unsigned short As[128 * 64];
    __shared__ __align__(16) unsigned short Ws[64 * 64];
    gemm2p_body<128, 64>(p, blockIdx.x, As, Ws, threadIdx.x);
}

// ---------------- row log_softmax (bf16-in, fp32-out) -----------------------
__device__ __forceinline__ void logsoftmax_row_b16(
    const unsigned short* __restrict__ lb, float* __restrict__ op, int tid)
{
    const int lane = tid & 63;
    const int wv = tid >> 6;
    __shared__ float redm[4];
    __shared__ float reds[4];

    uint4 r[2];
    r[0] = *(const uint4*)&lb[tid * 8];
    r[1] = *(const uint4*)&lb[2048 + tid * 8];
    float v[16];
#pragma unroll
    for (int h = 0; h < 2; ++h)
#pragma unroll
        for (int j = 0; j < 4; ++j) {
            unsigned u = ((const unsigned*)&r[h])[j];
            v[h * 8 + 2 * j]     = __uint_as_float(u << 16);
            v[h * 8 + 2 * j + 1] = __uint_as_float(u & 0xFFFF0000u);
        }

    float m = v[0];
#pragma unroll
    for (int i = 1; i < 16; ++i) m = fmaxf(m, v[i]);
#pragma unroll
    for (int off = 32; off; off >>= 1) m = fmaxf(m, __shfl_xor(m, off));
    if (lane == 0) redm[wv] = m;
    __syncthreads();
    m = fmaxf(fmaxf(redm[0], redm[1]), fmaxf(redm[2], redm[3]));

    float s = 0.f;
#pragma unroll
    for (int i = 0; i < 16; ++i) s += expf(v[i] - m);
#pragma unroll
    for (int off = 32; off; off >>= 1) s += __shfl_xor(s, off);
    if (lane == 0) reds[wv] = s;
    __syncthreads();
    s = reds[0] + reds[1] + reds[2] + reds[3];

    const float lse = m + logf(s);
#pragma unroll
    for (int h = 0; h < 2; ++h) {
        float4 o0, o1;
        o0.x = v[h*8+0]-lse; o0.y = v[h*8+1]-lse; o0.z = v[h*8+2]-lse; o0.w = v[h*8+3]-lse;
        o1.x = v[h*8+4]-lse; o1.y = v[h*8+5]-lse; o1.z = v[h*8+6]-lse; o1.w = v[h*8+7]-lse;
        *(float4*)&op[h * 2048 + tid * 8]     = o0;
        *(float4*)&op[h * 2048 + tid * 8 + 4] = o1;
    }
}

// GEMM2 at 128x64/BK64 (blocks 0..511) + log_softmax rows (512..4607)
__global__ __launch_bounds__(256) void g2sm_k(
    GemmP p, float* __restrict__ out, const unsigned short* __restrict__ lb16)
{
    if (blockIdx.x < 512) {
        __shared__ __align__(16) unsigned short As[128 * 64];
        __shared__ __align__(16) unsigned short Ws[64 * 64];
        gemm2p_body<128, 64>(p, blockIdx.x, As, Ws, threadIdx.x);
    } else {
        const int row = blockIdx.x - 512;
        logsoftmax_row_b16(lb16 + (size_t)row * 4096,
                           out + (size_t)row * 4096, threadIdx.x);
    }
}

// ============ per-phase counted 256x256 GEMM (GEMM3) — R13 form (locked) ====
// Schedule: p0 vmcnt(4);bar;rd af0,wfA;st A0(t+1);Q00 | p1 ...B1(t)... |
// p2 ...A1(t)... | p3 no-bar st A1(t+1) Q10. Tail 4/2/0. bf16 logits out.

__device__ __forceinline__ void stage_half8(
    const unsigned short* __restrict__ src, int ld, int base_rc, int tau, int h,
    unsigned short* lds, int wid, int lane, bool isA)
{
    unsigned short* dst = lds + (tau & 1) * 16384 + h * 8192 + wid * 1024;
    const int k0 = (tau & 15) << 6;
#pragma unroll
    for (int i = 0; i < 2; ++i) {
        int c = wid * 128 + i * 64 + lane;
        int ir = c >> 3, cc = c & 7;
        int grow = isA ? (base_rc + h * 64 + (ir & 63) + ((ir >> 6) << 7))
                       : (base_rc + h * 32 + (ir & 31) + ((ir >> 5) << 6));
        int gk = k0 + (((cc ^ ir) & 7) << 3);
        gload_lds16(src + (size_t)grow * ld + gk, dst + i * 512);
    }
}

__global__ __launch_bounds__(512, 2) void gemm8p(
    const unsigned short* __restrict__ Aa, const unsigned short* __restrict__ Ab,
    const unsigned short* __restrict__ Wa, const unsigned short* __restrict__ Wb,
    int lda, int ldw, const float* __restrict__ bias,
    unsigned short* __restrict__ Cb16, int ldc, int nx)
{
    constexpr int NT = 32;
    __shared__ __align__(16) unsigned short smem[65536];   // 128 KB
    unsigned short* As = smem;
    unsigned short* Bs = smem + 32768;

    int bid = blockIdx.x;
    bid = (bid & 7) * 32 + (bid >> 3);            // XCD swizzle (256 = 8*32)
    const int row0 = (bid / nx) * 256;
    const int col0 = (bid % nx) * 256;

    const int tid = threadIdx.x;
    const int wid = tid >> 6, lane = tid & 63;
    const int wr = wid >> 2, wc = wid & 3;        // 2 x 4 wave grid
    const int fr = lane & 15, fk = lane >> 4;
    const int ch0 = fk ^ (fr & 7);
    const int ch1 = ch0 ^ 4;

#define STA8(tau, h) stage_half8(((tau) < 16 ? Aa : Ab), lda, row0, (tau), (h), As, wid, lane, true)
#define STB8(tau, h) stage_half8(((tau) < 16 ? Wa : Wb), ldw, col0, (tau), (h), Bs, wid, lane, false)

#define LDAF(QM) { const unsigned short* Ap_ = Abase + (QM) * 8192;           \
    _Pragma("unroll") for (int mf = 0; mf < 4; ++mf) {                        \
        int ia = wr * 64 + mf * 16 + fr;                                      \
        af[mf][0] = *(const bf16x8*)&Ap_[ia * 64 + ch0 * 8];                  \
        af[mf][1] = *(const bf16x8*)&Ap_[ia * 64 + ch1 * 8]; } }

#define LDWF(QN, WF) { const unsigned short* Bp_ = Bbase + (QN) * 8192;       \
    _Pragma("unroll") for (int nf = 0; nf < 2; ++nf) {                        \
        int ib = wc * 32 + nf * 16 + fr;                                      \
        WF[nf][0] = *(const bf16x8*)&Bp_[ib * 64 + ch0 * 8];                  \
        WF[nf][1] = *(const bf16x8*)&Bp_[ib * 64 + ch1 * 8]; } }

#define MMQ(QM, QN, WF) {                                                     \
    __builtin_amdgcn_s_setprio(1);                                            \
    _Pragma("unroll") for (int mf = 0; mf < 4; ++mf)                          \
    _Pragma("unroll") for (int nf = 0; nf < 2; ++nf) {                        \
        acc[QM][QN][mf][nf] = __builtin_amdgcn_mfma_f32_16x16x32_bf16(        \
            af[mf][0], WF[nf][0], acc[QM][QN][mf][nf], 0, 0, 0);              \
        acc[QM][QN][mf][nf] = __builtin_amdgcn_mfma_f32_16x16x32_bf16(        \
            af[mf][1], WF[nf][1], acc[QM][QN][mf][nf], 0, 0, 0); }            \
    __builtin_amdgcn_s_setprio(0); }

    f32x4 acc[2][2][4][2] = {};
    bf16x8 af[4][2], wfA[2][2], wfB[2][2];

    // prologue: stage tile0's halves in consumption order A0,B0,B1,A1
    STA8(0, 0); STB8(0, 0); STB8(0, 1); STA8(0, 1);

    for (int t = 0; t < NT; ++t) {
        const unsigned short* Abase = As + (t & 1) * 16384;
        const unsigned short* Bbase = Bs + (t & 1) * 16384;
        const bool more = (t + 1 < NT);

        // p0: Q(0,0) — consumes A0(t),B0(t)
        asm volatile("s_waitcnt vmcnt(4)" ::: "memory");
        __builtin_amdgcn_s_barrier();
        LDAF(0); LDWF(0, wfA);
        if (more) STA8(t + 1, 0);
        MMQ(0, 0, wfA);

        // p1: Q(0,1) — consumes B1(t)
        if (more) { asm volatile("s_waitcnt vmcnt(4)" ::: "memory"); }
        else      { asm volatile("s_waitcnt vmcnt(2)" ::: "memory"); }
        __builtin_amdgcn_s_barrier();
        LDWF(1, wfB);
        if (more) STB8(t + 1, 0);
        MMQ(0, 1, wfB);

        // p2: Q(1,1) — consumes A1(t)
        if (more) { asm volatile("s_waitcnt vmcnt(4)" ::: "memory"); }
        else      { asm volatile("s_waitcnt vmcnt(0)" ::: "memory"); }
        __builtin_amdgcn_s_barrier();
        LDAF(1);
        if (more) STB8(t + 1, 1);
        MMQ(1, 1, wfB);

        // p3: Q(1,0) — zero ds_reads, no barrier
        if (more) STA8(t + 1, 1);
        MMQ(1, 0, wfA);
    }
#undef MMQ
#undef LDAF
#undef LDWF
#undef STA8
#undef STB8

    // epilogue: acc -> LDS (fp32, +bias, XOR de-conflict) -> bf16 ushort4
    float bv[2][2];
#pragma unroll
    for (int qn = 0; qn < 2; ++qn)
#pragma unroll
        for (int nf = 0; nf < 2; ++nf)
            bv[qn][nf] = bias[col0 + wc * 64 + qn * 32 + nf * 16 + fr];

    float* Ct = (float*)smem;                     // [128][256] fp32 = 128KB
    __syncthreads();
#pragma unroll
    for (int qm = 0; qm < 2; ++qm) {
        if (qm) __syncthreads();
#pragma unroll
        for (int qn = 0; qn < 2; ++qn)
#pragma unroll
            for (int nf = 0; nf < 2; ++nf) {
                const int col = wc * 64 + qn * 32 + nf * 16 + fr;
#pragma unroll
                for (int mf = 0; mf < 4; ++mf)
#pragma unroll
                    for (int j = 0; j < 4; ++j) {
                        int lr = wr * 64 + mf * 16 + fk * 4 + j;
                        int pc = col ^ (((lr >> 2) & 3) << 4);
                        Ct[lr * 256 + pc] = acc[qm][qn][mf][nf][j] + bv[qn][nf];
                    }
            }
        __syncthreads();
#pragma unroll
        for (int k = 0; k < 16; ++k) {
            int idx = k * 512 + tid;
            int lrow = idx >> 6, c4 = idx & 63;
            int pc4 = (c4 * 4) ^ (((lrow >> 2) & 3) << 4);
            int grow = row0 + qm * 64 + (lrow & 63) + ((lrow >> 6) << 7);
            float4 v = *(const float4*)&Ct[lrow * 256 + pc4];
            unsigned short o[4] = { f2b_rne(v.x), f2b_rne(v.y),
                                    f2b_rne(v.z), f2b_rne(v.w) };
            *(ushort4*)&Cb16[(size_t)grow * ldc + col0 + c4 * 4] =
                *(const ushort4*)o;
        }
    }
}

// ============================================================================
extern "C" void kernel_launch(void* const* d_in, const int* in_sizes, int n_in,
                              void* d_out, int out_size, void* d_ws, size_t ws_size,
                              hipStream_t stream)
{
    (void)in_sizes; (void)n_in; (void)out_size; (void)ws_size;

    const float* input  = (const float*)d_in[0];
    const float* hidden = (const float*)d_in[1];
    const float* b_ih0  = (const float*)d_in[4];
    const float* b_hh0  = (const float*)d_in[5];
    const float* b_ih1  = (const float*)d_in[8];
    const float* b_hh1  = (const float*)d_in[9];
    const float* b_out  = (const float*)d_in[11];

    float* out = (float*)d_out;                    // [4096,4096]
    float* h0  = out + (size_t)4096 * 4096;
    float* h1  = h0 + (size_t)4096 * 1024;

    unsigned short* xb    = (unsigned short*)d_ws;
    unsigned short* hidb  = xb    + (size_t)4096 * 1024;
    unsigned short* h0b   = hidb  + (size_t)2 * 4096 * 1024;
    unsigned short* Wih0b = h0b   + (size_t)4096 * 1024;
    unsigned short* Whh0b = Wih0b + (size_t)1024 * 1024;
    unsigned short* Wih1b = Whh0b + (size_t)1024 * 1024;
    unsigned short* Whh1b = Wih1b + (size_t)1024 * 1024;
    unsigned short* Woutb = Whh1b + (size_t)1024 * 1024;
    unsigned short* lb16  = Woutb + (size_t)4096 * 2048;   // bf16 logits, 32MB
    unsigned short* hid0b = hidb;
    unsigned short* hid1b = hidb + (size_t)4096 * 1024;

    // one standalone conversion pass
    CvtArgs ca;
    ca.seg[0] = { input,                 xb,    524288u };
    ca.seg[1] = { hidden,                hidb, 1048576u };
    ca.seg[2] = { (const float*)d_in[2], Wih0b, 131072u };
    ca.seg[3] = { (const float*)d_in[3], Whh0b, 131072u };
    ca.seg[4] = { (const float*)d_in[6], Wih1b, 131072u };
    ca.seg[5] = { (const float*)d_in[7], Whh1b, 131072u };
    ca.seg[6] = { (const float*)d_in[10],Woutb, 1048576u };
    ca.seg[7] = { nullptr, nullptr, 0u };
    hipLaunchKernelGGL(f2b_multi, dim3(12288), dim3(256), 0, stream, ca);

    // GEMM1: h0 = tanh(x@Wih0^T + hid0@Whh0^T + b), 128x64/BK64, 512 blocks
    GemmP p1;
    p1.Aa = xb;    p1.Ab = hid0b; p1.lda = 1024;
    p1.Wa = Wih0b; p1.Wb = Whh0b; p1.ldw = 1024;
    p1.ba = b_ih0; p1.bb = b_hh0;
    p1.C = h0; p1.ldc = 1024; p1.Cb = h0b; p1.ldcb = 1024;
    p1.nx = 16; p1.nb = 512; p1.do_tanh = 1;
    hipLaunchKernelGGL(gemm1_k, dim3(512), dim3(256), 0, stream, p1);

    // GEMM3: bf16 logits = x@W_out[:,:1024]^T + h0@W_out[:,1024:]^T + b_out
    hipLaunchKernelGGL(gemm8p, dim3(256), dim3(512), 0, stream,
                       xb, h0b, Woutb, Woutb + 1024, 1024, 2048,
                       b_out, lb16, 4096, 16);

    // GEMM2 at 128x64/BK64 (512 blocks) + log_softmax (4096 rows)
    GemmP p2;
    p2.Aa = h0b;   p2.Ab = hid1b; p2.lda = 1024;
    p2.Wa = Wih1b; p2.Wb = Whh1b; p2.ldw = 1024;
    p2.ba = b_ih1; p2.bb = b_hh1;
    p2.C = h1; p2.ldc = 1024; p2.Cb = nullptr; p2.ldcb = 0;
    p2.nx = 16; p2.nb = 512; p2.do_tanh = 1;
    hipLaunchKernelGGL(g2sm_k, dim3(4608), dim3(256), 0, stream, p2, out, lb16);
}